// Round 5
// baseline (55.515 us; speedup 1.0000x reference)
//
#include <hip/hip_runtime.h>
#include <hip/hip_bf16.h>
#include <stdint.h>

#define N_ATOMS 131072
#define D_IN    128
#define D_HID   256
#define N_ELEM  4
// each element bucket padded to a multiple of 64 (one wave's atom tile)
#define NPAD    (N_ATOMS + N_ELEM * 64)   // 131328 slots max
#define NTILES  (NPAD / 64)               // 2052
#define K4_BLOCKS (NTILES / 2)             // 1026, 2 tiles per block
#define K1_BLOCKS 512                      // 512*256 == N_ATOMS exactly

typedef __attribute__((ext_vector_type(8))) short bf16x8;
typedef __attribute__((ext_vector_type(4))) float f32x4;

// ws layout (bytes):
//   [0,       262144): W1t bf16 [4][256][128] (h-major, k contiguous)
//   [262144,  262160): counts[4]
//   [262176,  262200): startArr[5] (64-aligned bucket starts; [4]=padded total)
//   [262272,  266384): blockPartials[K4_BLOCKS] float
//   [270592,  278784): blockCounts[512][4] int
//   [278784,  286976): blockOff[512][4] int (scatter bases, deterministic)
//   [287232,  812544): sortedIdx[NPAD] int
#define WS_COUNTS 262144
#define WS_START  262176
#define WS_BPART  262272
#define WS_BCNT   270592
#define WS_BOFF   278784
#define WS_SIDX   287232

__device__ __forceinline__ unsigned short f2bf_rne(float f) {
    union { float f; unsigned u; } v; v.f = f;
    unsigned r = v.u + 0x7FFFu + ((v.u >> 16) & 1u);   // RNE
    return (unsigned short)(r >> 16);
}

// K1: per-block histogram (plain stores, no global atomics) + W1 -> W1t bf16.
// 4*128*256 == 131072 == N_ATOMS, one index space covers both jobs.
__global__ void tnn_k1_hist_w1t(const int* __restrict__ eid, int* __restrict__ bcnt,
                                const float* __restrict__ W1, unsigned short* __restrict__ W1t) {
    __shared__ int lc[N_ELEM];
    int t = threadIdx.x;
    if (t < N_ELEM) lc[t] = 0;
    __syncthreads();
    int i = blockIdx.x * 256 + t;          // always < N_ATOMS
    atomicAdd(&lc[eid[i]], 1);             // LDS atomic only
    // W1 flat index i = ((e*128)+k)*256 + h  ->  W1t[((e*256)+h)*128 + k]
    int e   = i >> 15;
    int rem = i & 32767;
    int k   = rem >> 8;
    int h   = rem & 255;
    W1t[(((e << 8) + h) << 7) + k] = f2bf_rne(W1[i]);
    __syncthreads();
    if (t < N_ELEM) bcnt[blockIdx.x * 4 + t] = lc[t];
}

// K2: one wave (64 threads), barrier-free shfl scan of blockCounts.
__global__ void tnn_k2_scan(const int* __restrict__ bcnt, int* __restrict__ counts,
                            int* __restrict__ startArr, int* __restrict__ boff) {
    int t = threadIdx.x;     // 0..63
    int4 c[8];
    int4 s = {0, 0, 0, 0};
    #pragma unroll
    for (int j = 0; j < 8; ++j) {
        c[j] = ((const int4*)bcnt)[t * 8 + j];
        s.x += c[j].x; s.y += c[j].y; s.z += c[j].z; s.w += c[j].w;
    }
    int4 incl = s;
    #pragma unroll
    for (int off = 1; off < 64; off <<= 1) {
        int ux = __shfl_up(incl.x, off);
        int uy = __shfl_up(incl.y, off);
        int uz = __shfl_up(incl.z, off);
        int uw = __shfl_up(incl.w, off);
        if (t >= off) { incl.x += ux; incl.y += uy; incl.z += uz; incl.w += uw; }
    }
    int4 tot = {__shfl(incl.x, 63), __shfl(incl.y, 63), __shfl(incl.z, 63), __shfl(incl.w, 63)};
    int st0 = 0;
    int st1 = st0 + ((tot.x + 63) & ~63);
    int st2 = st1 + ((tot.y + 63) & ~63);
    int st3 = st2 + ((tot.z + 63) & ~63);
    int st4 = st3 + ((tot.w + 63) & ~63);
    int4 run = {incl.x - s.x, incl.y - s.y, incl.z - s.z, incl.w - s.w};  // exclusive
    #pragma unroll
    for (int j = 0; j < 8; ++j) {
        int4 o = {st0 + run.x, st1 + run.y, st2 + run.z, st3 + run.w};
        ((int4*)boff)[t * 8 + j] = o;
        run.x += c[j].x; run.y += c[j].y; run.z += c[j].z; run.w += c[j].w;
    }
    if (t == 0) {
        ((int4*)counts)[0] = tot;
        startArr[0] = st0; startArr[1] = st1; startArr[2] = st2;
        startArr[3] = st3; startArr[4] = st4;
    }
}

// K3: scatter with deterministic per-block bases (LDS rank atomics only).
__global__ void tnn_k3_scatter(const int* __restrict__ eid, const int* __restrict__ boff,
                               int* __restrict__ sortedIdx) {
    __shared__ int lc[N_ELEM];
    int t = threadIdx.x;
    if (t < N_ELEM) lc[t] = 0;
    __syncthreads();
    int i = blockIdx.x * 256 + t;          // always < N_ATOMS
    int e = eid[i];
    int rank = atomicAdd(&lc[e], 1);
    sortedIdx[boff[blockIdx.x * 4 + e] + rank] = i;
}

// K4: block = two 64-atom tiles, double-buffered LDS staging (bf16, XOR-swizzled).
// Tile t+1's global loads are issued before tile t's compute -> latency hidden.
__global__ __launch_bounds__(256, 4) void tnn_k4_mlp(
        const float* __restrict__ X, const int* __restrict__ sortedIdx,
        const int* __restrict__ startArr, const int* __restrict__ counts,
        const unsigned short* __restrict__ W1t, const float* __restrict__ b1,
        const float* __restrict__ W2, float* __restrict__ bpart) {
    __shared__ unsigned char lds[2][64 * 128 * 2];   // 2 x 16 KB A-tiles
    __shared__ float red[4];
    const float C2 = 2.8853900817779268f;            // 2*log2(e)

    int t = threadIdx.x;
    int wid  = t >> 6;
    int lane = t & 63;
    int l15 = lane & 15;
    int lk  = lane >> 4;
    // staging mapping: thread covers 128 contiguous bytes of one atom row
    int srow   = t >> 2;                    // 0..63
    int schunk = t & 3;                     // 0..3
    unsigned ldsbase = srow * 256 + schunk * 64;
    unsigned swb     = (srow & 7) << 4;

    int tb0 = blockIdx.x * 128;             // tile0 base slot
    int tb1 = tb0 + 64;
    int total = startArr[N_ELEM];
    bool act0 = (tb0 < total);
    bool act1 = (tb1 < total);

    // per-tile meta (wave-uniform)
    int e0 = 0, end0 = 0, e1 = 0, end1 = 0;
    if (act0) {
        while (tb0 >= startArr[e0 + 1]) ++e0;
        end0 = startArr[e0] + counts[e0];
    }
    if (act1) {
        e1 = e0;
        while (tb1 >= startArr[e1 + 1]) ++e1;
        end1 = startArr[e1] + counts[e1];
    }

    f32x4 v[8];
    auto stage_load = [&](int tb, int rend) {
        int slot = tb + srow;
        int g = (slot < rend) ? sortedIdx[slot] : sortedIdx[tb];
        const float* xr = X + (size_t)g * D_IN + schunk * 32;
        #pragma unroll
        for (int j = 0; j < 8; ++j) v[j] = *(const f32x4*)(xr + j * 4);
    };
    auto stage_write = [&](unsigned char* lb) {
        #pragma unroll
        for (int j = 0; j < 4; ++j) {
            f32x4 v0 = v[2 * j], v1 = v[2 * j + 1];
            bf16x8 tv;
            tv[0] = (short)(__float_as_uint(v0[0]) >> 16);
            tv[1] = (short)(__float_as_uint(v0[1]) >> 16);
            tv[2] = (short)(__float_as_uint(v0[2]) >> 16);
            tv[3] = (short)(__float_as_uint(v0[3]) >> 16);
            tv[4] = (short)(__float_as_uint(v1[0]) >> 16);
            tv[5] = (short)(__float_as_uint(v1[1]) >> 16);
            tv[6] = (short)(__float_as_uint(v1[2]) >> 16);
            tv[7] = (short)(__float_as_uint(v1[3]) >> 16);
            *(bf16x8*)(&lb[(ldsbase + j * 16) ^ swb]) = tv;
        }
    };

    auto compute = [&](const unsigned char* lb, int e, int tb, int rend) -> float {
        bool full = (tb + 64 <= rend);
        const unsigned short* wr = W1t + (size_t)e * D_HID * D_IN
                                       + (size_t)(wid * 64 + l15) * D_IN + lk * 8;
        const float* b1p = b1 + e * D_HID + wid * 64 + l15;
        const float* w2p = W2 + e * D_HID + wid * 64 + l15;
        float b1v[4], w2v[4];
        #pragma unroll
        for (int nt = 0; nt < 4; ++nt) { b1v[nt] = b1p[nt * 16]; w2v[nt] = w2p[nt * 16]; }

        float fnval = 16.f;
        if (!full) {
            int nv = 0;
            #pragma unroll
            for (int m = 0; m < 4; ++m)
                #pragma unroll
                for (int r = 0; r < 4; ++r)
                    nv += (tb + m * 16 + lk * 4 + r < rend) ? 1 : 0;
            fnval = (float)nv;
        }

        float part = 0.f;
        #pragma unroll
        for (int nt = 0; nt < 4; ++nt) {
            const unsigned short* wn = wr + (size_t)nt * 16 * D_IN;
            bf16x8 cur0 = *(const bf16x8*)(wn);
            bf16x8 cur1 = *(const bf16x8*)(wn + 32);
            bf16x8 cur2 = *(const bf16x8*)(wn + 64);
            bf16x8 cur3 = *(const bf16x8*)(wn + 96);

            f32x4 acc[4];
            #pragma unroll
            for (int m = 0; m < 4; ++m) {
                int row = m * 16 + l15;
                unsigned base = row * 256 + lk * 16;
                unsigned sw2  = (row & 7) << 4;
                bf16x8 a0 = *(const bf16x8*)(&lb[(base      ) ^ sw2]);
                bf16x8 a1 = *(const bf16x8*)(&lb[(base +  64) ^ sw2]);
                bf16x8 a2 = *(const bf16x8*)(&lb[(base + 128) ^ sw2]);
                bf16x8 a3 = *(const bf16x8*)(&lb[(base + 192) ^ sw2]);
                acc[m] = f32x4{0.f, 0.f, 0.f, 0.f};
                acc[m] = __builtin_amdgcn_mfma_f32_16x16x32_bf16(a0, cur0, acc[m], 0, 0, 0);
                acc[m] = __builtin_amdgcn_mfma_f32_16x16x32_bf16(a1, cur1, acc[m], 0, 0, 0);
                acc[m] = __builtin_amdgcn_mfma_f32_16x16x32_bf16(a2, cur2, acc[m], 0, 0, 0);
                acc[m] = __builtin_amdgcn_mfma_f32_16x16x32_bf16(a3, cur3, acc[m], 0, 0, 0);
            }

            // tanh(p) = 1 - 2/(exp2(C2*p)+1);  sum w2*tanh = w2*(nval - 2*sum(rcp))
            float b1s = b1v[nt] * C2;
            float rsum = 0.f;
            #pragma unroll
            for (int m = 0; m < 4; ++m) {
                #pragma unroll
                for (int r = 0; r < 4; ++r) {
                    float exv = __builtin_amdgcn_exp2f(fmaf(C2, acc[m][r], b1s));
                    float rc  = __builtin_amdgcn_rcpf(exv + 1.f);
                    if (!full)
                        rc = (tb + m * 16 + lk * 4 + r < rend) ? rc : 0.f;
                    rsum += rc;
                }
            }
            part = fmaf(w2v[nt], fmaf(-2.f, rsum, fnval), part);
        }
        return part;
    };

    float partial = 0.f;

    // pipeline: stage0 | sync | load1 ; compute0 ; write1 | sync | compute1
    if (act0) { stage_load(tb0, end0); stage_write(&lds[0][0]); }
    __syncthreads();
    if (act1) stage_load(tb1, end1);
    if (act0) partial += compute(&lds[0][0], e0, tb0, end0);
    if (act1) stage_write(&lds[1][0]);
    __syncthreads();
    if (act1) partial += compute(&lds[1][0], e1, tb1, end1);

    #pragma unroll
    for (int off = 32; off; off >>= 1)
        partial += __shfl_down(partial, off);
    if (lane == 0) red[wid] = partial;
    __syncthreads();
    if (t == 0)
        bpart[blockIdx.x] = red[0] + red[1] + red[2] + red[3];   // plain store
}

// K5: single block reduces block partials + analytic bias term.
__global__ void tnn_k5_reduce(const float* __restrict__ bpart, const int* __restrict__ counts,
                              const float* __restrict__ b2, float* __restrict__ out) {
    __shared__ float r[4];
    int t = threadIdx.x;
    float s = 0.f;
    for (int i = t; i < K4_BLOCKS; i += 256) s += bpart[i];
    #pragma unroll
    for (int off = 32; off; off >>= 1)
        s += __shfl_down(s, off);
    if ((t & 63) == 0) r[t >> 6] = s;
    __syncthreads();
    if (t == 0) {
        float acc = r[0] + r[1] + r[2] + r[3];
        #pragma unroll
        for (int e = 0; e < N_ELEM; ++e)
            acc += (float)counts[e] * b2[e];   // b2 is [E,1]
        out[0] = acc;
    }
}

extern "C" void kernel_launch(void* const* d_in, const int* in_sizes, int n_in,
                              void* d_out, int out_size, void* d_ws, size_t ws_size,
                              hipStream_t stream) {
    const float* X   = (const float*)d_in[0];
    const int*   eid = (const int*)  d_in[1];
    const float* W1  = (const float*)d_in[2];
    const float* b1  = (const float*)d_in[3];
    const float* W2  = (const float*)d_in[4];
    const float* b2  = (const float*)d_in[5];
    float* out = (float*)d_out;

    char* ws = (char*)d_ws;
    unsigned short* W1t = (unsigned short*)ws;
    int*   counts    = (int*)  (ws + WS_COUNTS);
    int*   startArr  = (int*)  (ws + WS_START);
    float* bpart     = (float*)(ws + WS_BPART);
    int*   bcnt      = (int*)  (ws + WS_BCNT);
    int*   boff      = (int*)  (ws + WS_BOFF);
    int*   sortedIdx = (int*)  (ws + WS_SIDX);

    hipLaunchKernelGGL(tnn_k1_hist_w1t, dim3(K1_BLOCKS), dim3(256), 0, stream, eid, bcnt, W1, W1t);
    hipLaunchKernelGGL(tnn_k2_scan,     dim3(1),         dim3(64),  0, stream, bcnt, counts, startArr, boff);
    hipLaunchKernelGGL(tnn_k3_scatter,  dim3(K1_BLOCKS), dim3(256), 0, stream, eid, boff, sortedIdx);
    hipLaunchKernelGGL(tnn_k4_mlp,      dim3(K4_BLOCKS), dim3(256), 0, stream,
                       X, sortedIdx, startArr, counts, W1t, b1, W2, bpart);
    hipLaunchKernelGGL(tnn_k5_reduce,   dim3(1),         dim3(256), 0, stream, bpart, counts, b2, out);
}